// Round 8
// baseline (62.324 us; speedup 1.0000x reference)
//
#include <hip/hip_runtime.h>
#include <math.h>

// PseudoGroupContrast — queue-resident, register-staged, ILP-maximal.
//
//   grid = B/512, block = 1024 (16 waves), 1 block/CU (LDS ~111 KB).
//   No global_load_lds, no manual waitcnt: act/ema/queue loads are issued in
//   wide independent batches (~30 float4 in flight/wave) and the compiler
//   schedules the waits. Queue staged fp32->bf16 into LDS once per block.
//
//   af = bf16(2*inva*act) -> MFMA acc = 2*dot
//   S1 = sum exp(2*dot) (9 zero pad rows -> subtract 9)
//   S2 = label-block sum of acc;  def2 = 2*dot(f_hat, ef_hat)
//   per = log(exp(def2)+S1-9) - (S2+def2)/126;  out = sum(mask*per)/B

#define D        128
#define NQ       375
#define NQP      384
#define QS       125
#define RPB      512          // rows per block (16 waves x 32)
#define RSTRIDE  272          // queue LDS row stride (bytes); b128 reads bank-uniform
#define NTILES   24
#define INV126   (1.0f/126.0f)
#define QF4      12000        // queue float4 count (375*32)

typedef __attribute__((ext_vector_type(8))) short short8;
typedef __attribute__((ext_vector_type(4))) float f32x4;

static __device__ __forceinline__ unsigned f2bf2(float lo, float hi) {
    unsigned a = __float_as_uint(lo), b = __float_as_uint(hi);
    a = (a + 0x7fff + ((a >> 16) & 1)) >> 16;
    b = (b + 0x7fff + ((b >> 16) & 1)) >> 16;
    return (a & 0xffff) | (b << 16);
}

static __device__ __forceinline__ short8 pack8(float gs, float4 a, float4 b) {
    union { unsigned u[4]; short8 s; } r;
    r.u[0] = f2bf2(gs * a.x, gs * a.y);
    r.u[1] = f2bf2(gs * a.z, gs * a.w);
    r.u[2] = f2bf2(gs * b.x, gs * b.y);
    r.u[3] = f2bf2(gs * b.z, gs * b.w);
    return r.s;
}

static __device__ __forceinline__ float bf2f(short s) {
    return __uint_as_float(((unsigned)(unsigned short)s) << 16);
}

__global__ __launch_bounds__(1024, 4) void pgc_main(
    const float* __restrict__ act,
    const float* __restrict__ ema,
    const float* __restrict__ plab,
    const float* __restrict__ mask,
    const float* __restrict__ queue,
    float* __restrict__ out,
    int B, float invB)
{
    __shared__ unsigned char q_lds[NQP * RSTRIDE];   // 104448 B
    __shared__ float s_def2[RPB];
    __shared__ float s_mask[RPB];
    __shared__ int   s_lab[RPB];
    __shared__ float s_red[16];

    const int tid = threadIdx.x;
    const int w   = tid >> 6;
    const int l   = tid & 63;
    const int lr  = l & 15;       // fragment row / C col
    const int seg = l >> 4;       // k-segment / C row group
    const long blockBase = (long)blockIdx.x * RPB;
    const float4* q4 = (const float4*)queue;

    // ---- queue batch A: slots [0, 6144) ----
    float4 qa[6];
    #pragma unroll
    for (int i = 0; i < 6; ++i) {
        int fi = i * 1024 + tid;
        qa[i] = q4[fi < QF4 ? fi : 0];
    }

    // ---- mask / pseudo-label for row `tid` ----
    float mk = 0.f; int lb = 0;
    if (tid < RPB) {
        long grow = blockBase + tid;
        bool valid = grow < (long)B;
        long g2 = valid ? grow : (long)B - 1;
        mk = valid ? mask[g2] : 0.f;
        const float* p = plab + g2 * 3;
        float p0 = p[0], p1 = p[1], p2 = p[2];
        float bst = p0;
        if (p1 > bst) { bst = p1; lb = 1; }   // first-max tie-break = argmax
        if (p2 > bst) { lb = 2; }
    }

    // ---- act: issue BOTH row-groups' loads (16 float4 in flight) ----
    long grow0 = blockBase + w * 32 + lr;        // g=0 row
    long grow1 = grow0 + 16;                     // g=1 row
    if (grow0 >= (long)B) grow0 = (long)B - 1;
    if (grow1 >= (long)B) grow1 = (long)B - 1;

    float4 av0[8], av1[8];
    {
        const float4* a0 = (const float4*)(act + grow0 * D) + seg * 8;
        const float4* a1 = (const float4*)(act + grow1 * D) + seg * 8;
        #pragma unroll
        for (int i = 0; i < 8; ++i) av0[i] = a0[i];
        #pragma unroll
        for (int i = 0; i < 8; ++i) av1[i] = a1[i];
    }

    short8 af[2][4];
    float gs0, gs1;
    {
        float sa0 = 0.f, sa1 = 0.f;
        #pragma unroll
        for (int i = 0; i < 8; ++i) {
            sa0 += av0[i].x*av0[i].x + av0[i].y*av0[i].y + av0[i].z*av0[i].z + av0[i].w*av0[i].w;
            sa1 += av1[i].x*av1[i].x + av1[i].y*av1[i].y + av1[i].z*av1[i].z + av1[i].w*av1[i].w;
        }
        sa0 += __shfl_xor(sa0, 16); sa0 += __shfl_xor(sa0, 32);
        sa1 += __shfl_xor(sa1, 16); sa1 += __shfl_xor(sa1, 32);
        gs0 = 2.0f / fmaxf(sqrtf(sa0), 1e-12f);
        gs1 = 2.0f / fmaxf(sqrtf(sa1), 1e-12f);
        #pragma unroll
        for (int ks = 0; ks < 4; ++ks) {
            af[0][ks] = pack8(gs0, av0[2 * ks], av0[2 * ks + 1]);
            af[1][ks] = pack8(gs1, av1[2 * ks], av1[2 * ks + 1]);
        }
    }

    // ---- write queue batch A to LDS (frees qa regs) ----
    #pragma unroll
    for (int i = 0; i < 6; ++i) {
        int fi = i * 1024 + tid;
        int row = fi >> 5, c4 = fi & 31;
        float4 v = (row < NQ) ? qa[i] : make_float4(0.f, 0.f, 0.f, 0.f);
        uint2 wv; wv.x = f2bf2(v.x, v.y); wv.y = f2bf2(v.z, v.w);
        *(uint2*)&q_lds[row * RSTRIDE + c4 * 8] = wv;
    }

    // ---- queue batch B: slots [6144, 12288) ----
    float4 qb[6];
    #pragma unroll
    for (int i = 0; i < 6; ++i) {
        int fi = 6144 + i * 1024 + tid;
        qb[i] = q4[fi < QF4 ? fi : 0];
    }

    // ---- ema: both groups' loads, then sse/dae vs bf16 af ----
    {
        const float4* e0 = (const float4*)(ema + grow0 * D) + seg * 8;
        const float4* e1 = (const float4*)(ema + grow1 * D) + seg * 8;
        float4 ev0[8], ev1[8];
        #pragma unroll
        for (int i = 0; i < 8; ++i) ev0[i] = e0[i];
        #pragma unroll
        for (int i = 0; i < 8; ++i) ev1[i] = e1[i];

        float ss0 = 0.f, ss1 = 0.f, da0 = 0.f, da1 = 0.f;
        #pragma unroll
        for (int ks = 0; ks < 4; ++ks) {
            short8 a0 = af[0][ks], a1 = af[1][ks];
            float4 x0 = ev0[2*ks], y0 = ev0[2*ks+1];
            float4 x1 = ev1[2*ks], y1 = ev1[2*ks+1];
            ss0 += x0.x*x0.x + x0.y*x0.y + x0.z*x0.z + x0.w*x0.w
                 + y0.x*y0.x + y0.y*y0.y + y0.z*y0.z + y0.w*y0.w;
            ss1 += x1.x*x1.x + x1.y*x1.y + x1.z*x1.z + x1.w*x1.w
                 + y1.x*y1.x + y1.y*y1.y + y1.z*y1.z + y1.w*y1.w;
            da0 += bf2f(a0[0])*x0.x + bf2f(a0[1])*x0.y + bf2f(a0[2])*x0.z + bf2f(a0[3])*x0.w
                 + bf2f(a0[4])*y0.x + bf2f(a0[5])*y0.y + bf2f(a0[6])*y0.z + bf2f(a0[7])*y0.w;
            da1 += bf2f(a1[0])*x1.x + bf2f(a1[1])*x1.y + bf2f(a1[2])*x1.z + bf2f(a1[3])*x1.w
                 + bf2f(a1[4])*y1.x + bf2f(a1[5])*y1.y + bf2f(a1[6])*y1.z + bf2f(a1[7])*y1.w;
        }
        ss0 += __shfl_xor(ss0, 16); ss0 += __shfl_xor(ss0, 32);
        ss1 += __shfl_xor(ss1, 16); ss1 += __shfl_xor(ss1, 32);
        da0 += __shfl_xor(da0, 16); da0 += __shfl_xor(da0, 32);
        da1 += __shfl_xor(da1, 16); da1 += __shfl_xor(da1, 32);
        if (seg == 0) {
            // da already carries the 2*inva factor via bf16(af); add 1/||e||
            s_def2[w * 32 + lr]      = da0 / fmaxf(sqrtf(ss0), 1e-12f);
            s_def2[w * 32 + 16 + lr] = da1 / fmaxf(sqrtf(ss1), 1e-12f);
        }
    }

    // ---- write queue batch B + per-row scalars ----
    #pragma unroll
    for (int i = 0; i < 6; ++i) {
        int fi = 6144 + i * 1024 + tid;
        int row = fi >> 5, c4 = fi & 31;
        float4 v = (row < NQ) ? qb[i] : make_float4(0.f, 0.f, 0.f, 0.f);
        uint2 wv; wv.x = f2bf2(v.x, v.y); wv.y = f2bf2(v.z, v.w);
        *(uint2*)&q_lds[row * RSTRIDE + c4 * 8] = wv;
    }
    if (tid < RPB) { s_mask[tid] = mk; s_lab[tid] = lb; }

    __syncthreads();   // the only pre-epilogue barrier

    // ---- label-block starts for this lane's C rows ----
    int lo8[2][4];
    #pragma unroll
    for (int g = 0; g < 2; ++g)
        #pragma unroll
        for (int r = 0; r < 4; ++r)
            lo8[g][r] = s_lab[w * 32 + g * 16 + seg * 4 + r] * QS;

    float S1[2][4] = {{0.f,0.f,0.f,0.f},{0.f,0.f,0.f,0.f}};
    float S2[2][4] = {{0.f,0.f,0.f,0.f},{0.f,0.f,0.f,0.f}};

    #pragma unroll 4
    for (int nt = 0; nt < NTILES; ++nt) {
        const unsigned char* bp = &q_lds[(nt * 16 + lr) * RSTRIDE + seg * 16];
        short8 b0 = *(const short8*)(bp);
        short8 b1 = *(const short8*)(bp + 64);
        short8 b2 = *(const short8*)(bp + 128);
        short8 b3 = *(const short8*)(bp + 192);
        const int col = nt * 16 + lr;
        #pragma unroll
        for (int g = 0; g < 2; ++g) {
            f32x4 acc = {0.f, 0.f, 0.f, 0.f};
            acc = __builtin_amdgcn_mfma_f32_16x16x32_bf16(af[g][0], b0, acc, 0, 0, 0);
            acc = __builtin_amdgcn_mfma_f32_16x16x32_bf16(af[g][1], b1, acc, 0, 0, 0);
            acc = __builtin_amdgcn_mfma_f32_16x16x32_bf16(af[g][2], b2, acc, 0, 0, 0);
            acc = __builtin_amdgcn_mfma_f32_16x16x32_bf16(af[g][3], b3, acc, 0, 0, 0);
            #pragma unroll
            for (int r = 0; r < 4; ++r) {
                S1[g][r] += __expf(acc[r]);
                if ((unsigned)(col - lo8[g][r]) < (unsigned)QS)
                    S2[g][r] += acc[r];
            }
        }
    }

    // ---- reduce over the 16 column lanes ----
    #pragma unroll
    for (int g = 0; g < 2; ++g)
        #pragma unroll
        for (int r = 0; r < 4; ++r) {
            S1[g][r] += __shfl_xor(S1[g][r], 1);
            S1[g][r] += __shfl_xor(S1[g][r], 2);
            S1[g][r] += __shfl_xor(S1[g][r], 4);
            S1[g][r] += __shfl_xor(S1[g][r], 8);
            S2[g][r] += __shfl_xor(S2[g][r], 1);
            S2[g][r] += __shfl_xor(S2[g][r], 2);
            S2[g][r] += __shfl_xor(S2[g][r], 4);
            S2[g][r] += __shfl_xor(S2[g][r], 8);
        }

    float contrib = 0.f;
    if (lr == 0) {
        #pragma unroll
        for (int g = 0; g < 2; ++g)
            #pragma unroll
            for (int r = 0; r < 4; ++r) {
                const int m = w * 32 + g * 16 + seg * 4 + r;
                const float def2  = s_def2[m];
                const float denom = __expf(def2) + S1[g][r] - 9.0f;
                const float per   = __logf(denom) - (S2[g][r] + def2) * INV126;
                contrib += s_mask[m] * per;
            }
    }
    contrib += __shfl_xor(contrib, 16);
    contrib += __shfl_xor(contrib, 32);
    if (l == 0) s_red[w] = contrib;
    __syncthreads();
    if (w == 0) {
        float v = (l < 16) ? s_red[l] : 0.f;
        v += __shfl_xor(v, 1); v += __shfl_xor(v, 2);
        v += __shfl_xor(v, 4); v += __shfl_xor(v, 8);
        if (l == 0) atomicAdd(out, v * invB);
    }
}

extern "C" void kernel_launch(void* const* d_in, const int* in_sizes, int n_in,
                              void* d_out, int out_size, void* d_ws, size_t ws_size,
                              hipStream_t stream)
{
    const float* act   = (const float*)d_in[0];
    const float* ema   = (const float*)d_in[1];
    const float* plab  = (const float*)d_in[2];
    const float* mask  = (const float*)d_in[3];
    const float* queue = (const float*)d_in[4];
    float* out = (float*)d_out;

    const int B = in_sizes[0] / D;

    hipMemsetAsync(out, 0, sizeof(float), stream);

    const int grid = (B + RPB - 1) / RPB;   // 256 for B=131072 -> 1 block/CU
    pgc_main<<<grid, 1024, 0, stream>>>(act, ema, plab, mask, queue, out,
                                        B, 1.0f / (float)B);
}